// Round 1
// baseline (2231.023 us; speedup 1.0000x reference)
//
#include <hip/hip_runtime.h>

// Problem constants (from reference): N=100000 rows, D=128, E=1000000 updates.
#define NROWS 100000
#define DDIM  128
#define ECNT  1000000

// Kernel 1: out = A  (vectorized float4 copy, fully coalesced)
__global__ void copy_A_kernel(const float4* __restrict__ A,
                              float4* __restrict__ out, int n4) {
    int i = blockIdx.x * blockDim.x + threadIdx.x;
    if (i < n4) out[i] = A[i];
}

// Kernel 2: scatter-add B into out rows given by index.
// 32 threads cooperate on one update e: lane c handles floats [4c, 4c+4).
// B read is a coalesced float4 per lane; adds are HW global_atomic_add_f32.
__global__ void scatter_B_kernel(const int* __restrict__ index,
                                 const float4* __restrict__ B,
                                 float* __restrict__ out) {
    int tid = blockIdx.x * blockDim.x + threadIdx.x;
    int e = tid >> 5;        // update id
    int c = tid & 31;        // float4 chunk within the row (D/4 = 32)
    if (e >= ECNT) return;
    int row = index[e];
    float4 b = B[(size_t)e * (DDIM / 4) + c];
    float* dst = out + (size_t)row * DDIM + c * 4;
    unsafeAtomicAdd(dst + 0, b.x);
    unsafeAtomicAdd(dst + 1, b.y);
    unsafeAtomicAdd(dst + 2, b.z);
    unsafeAtomicAdd(dst + 3, b.w);
}

extern "C" void kernel_launch(void* const* d_in, const int* in_sizes, int n_in,
                              void* d_out, int out_size, void* d_ws, size_t ws_size,
                              hipStream_t stream) {
    const int*    index = (const int*)d_in[0];
    const float*  A     = (const float*)d_in[1];
    const float*  B     = (const float*)d_in[2];
    float*        out   = (float*)d_out;

    // 1) out = A
    int n4 = NROWS * DDIM / 4;
    copy_A_kernel<<<(n4 + 255) / 256, 256, 0, stream>>>(
        (const float4*)A, (float4*)out, n4);

    // 2) out[index[e]] += B[e]
    long long threads = (long long)ECNT * 32;
    int blocks = (int)((threads + 255) / 256);
    scatter_B_kernel<<<blocks, 256, 0, stream>>>(index, (const float4*)B, out);
}

// Round 2
// 818.986 us; speedup vs baseline: 2.7241x; 2.7241x over previous
//
#include <hip/hip_runtime.h>

// Problem constants (from reference): N=100000 rows, D=128, E=1000000 updates.
#define NROWS 100000
#define DDIM  128
#define ECNT  1000000

#define SCAN_BLOCK 256
#define NB1 ((NROWS + SCAN_BLOCK - 1) / SCAN_BLOCK)   // 391 blocks

// ---------- 1) zero the histogram ----------
__global__ void zero_counts(int* __restrict__ counts) {
    int i = blockIdx.x * blockDim.x + threadIdx.x;
    if (i < NROWS) counts[i] = 0;
}

// ---------- 2) histogram of index ----------
__global__ void hist_kernel(const int* __restrict__ index, int* __restrict__ counts) {
    int e = blockIdx.x * blockDim.x + threadIdx.x;
    if (e < ECNT) atomicAdd(&counts[index[e]], 1);
}

// ---------- 3) multi-block exclusive scan ----------
__global__ void scan1(const int* __restrict__ counts, int* __restrict__ offsets,
                      int* __restrict__ block_sums) {
    __shared__ int tmp[SCAN_BLOCK];
    int t = threadIdx.x;
    int i = blockIdx.x * SCAN_BLOCK + t;
    int v = (i < NROWS) ? counts[i] : 0;
    tmp[t] = v;
    __syncthreads();
    for (int d = 1; d < SCAN_BLOCK; d <<= 1) {
        int add = (t >= d) ? tmp[t - d] : 0;
        __syncthreads();
        tmp[t] += add;
        __syncthreads();
    }
    if (i < NROWS) offsets[i] = tmp[t] - v;            // exclusive
    if (t == SCAN_BLOCK - 1) block_sums[blockIdx.x] = tmp[t];
}

__global__ void scan2(int* __restrict__ block_sums) {   // single block of 512
    __shared__ int tmp[512];
    int t = threadIdx.x;
    int v = (t < NB1) ? block_sums[t] : 0;
    tmp[t] = v;
    __syncthreads();
    for (int d = 1; d < 512; d <<= 1) {
        int add = (t >= d) ? tmp[t - d] : 0;
        __syncthreads();
        tmp[t] += add;
        __syncthreads();
    }
    if (t < NB1) block_sums[t] = tmp[t] - v;            // exclusive
}

__global__ void scan3(int* __restrict__ offsets, int* __restrict__ cursors,
                      const int* __restrict__ block_sums) {
    int i = blockIdx.x * SCAN_BLOCK + threadIdx.x;
    if (i < NROWS) {
        int o = offsets[i] + block_sums[blockIdx.x];
        offsets[i] = o;
        cursors[i] = o;
    }
}

// ---------- 4) build permutation (bucket the update ids by row) ----------
__global__ void scatter_perm(const int* __restrict__ index, int* __restrict__ cursors,
                             int* __restrict__ perm) {
    int e = blockIdx.x * blockDim.x + threadIdx.x;
    if (e < ECNT) {
        int r = index[e];
        int p = atomicAdd(&cursors[r], 1);
        perm[p] = e;
    }
}

// ---------- 5) gather: one wave per output row, no atomics ----------
__global__ void gather_rows(const float* __restrict__ A, const float* __restrict__ B,
                            const int* __restrict__ perm, const int* __restrict__ offsets,
                            const int* __restrict__ counts, float* __restrict__ out) {
    int wave = (blockIdx.x * blockDim.x + threadIdx.x) >> 6;  // row id
    int lane = threadIdx.x & 63;
    if (wave >= NROWS) return;

    int start = offsets[wave];
    int cnt   = counts[wave];

    const float2* Arow = (const float2*)(A + (size_t)wave * DDIM);
    float2 acc = Arow[lane];   // 64 lanes x 8B = full 128-float row, coalesced

    for (int base = 0; base < cnt; base += 64) {
        int m = cnt - base;
        if (m > 64) m = 64;
        // one coalesced load of up to 64 perm entries, then shfl-broadcast
        int myperm = (lane < m) ? perm[start + base + lane] : 0;
        int j = 0;
        for (; j + 4 <= m; j += 4) {
            int e0 = __shfl(myperm, j + 0);
            int e1 = __shfl(myperm, j + 1);
            int e2 = __shfl(myperm, j + 2);
            int e3 = __shfl(myperm, j + 3);
            float2 b0 = ((const float2*)(B + (size_t)e0 * DDIM))[lane];
            float2 b1 = ((const float2*)(B + (size_t)e1 * DDIM))[lane];
            float2 b2 = ((const float2*)(B + (size_t)e2 * DDIM))[lane];
            float2 b3 = ((const float2*)(B + (size_t)e3 * DDIM))[lane];
            acc.x += b0.x; acc.y += b0.y;
            acc.x += b1.x; acc.y += b1.y;
            acc.x += b2.x; acc.y += b2.y;
            acc.x += b3.x; acc.y += b3.y;
        }
        for (; j < m; ++j) {
            int e = __shfl(myperm, j);
            float2 b = ((const float2*)(B + (size_t)e * DDIM))[lane];
            acc.x += b.x; acc.y += b.y;
        }
    }

    float2* Orow = (float2*)(out + (size_t)wave * DDIM);
    Orow[lane] = acc;
}

extern "C" void kernel_launch(void* const* d_in, const int* in_sizes, int n_in,
                              void* d_out, int out_size, void* d_ws, size_t ws_size,
                              hipStream_t stream) {
    const int*   index = (const int*)d_in[0];
    const float* A     = (const float*)d_in[1];
    const float* B     = (const float*)d_in[2];
    float*       out   = (float*)d_out;

    // workspace layout (ints): counts[N] | offsets[N] | cursors[N] | block_sums[512] | perm[E]
    int* counts     = (int*)d_ws;
    int* offsets    = counts + NROWS;
    int* cursors    = offsets + NROWS;
    int* block_sums = cursors + NROWS;
    int* perm       = block_sums + 512;

    zero_counts<<<NB1, SCAN_BLOCK, 0, stream>>>(counts);
    hist_kernel<<<(ECNT + 255) / 256, 256, 0, stream>>>(index, counts);
    scan1<<<NB1, SCAN_BLOCK, 0, stream>>>(counts, offsets, block_sums);
    scan2<<<1, 512, 0, stream>>>(block_sums);
    scan3<<<NB1, SCAN_BLOCK, 0, stream>>>(offsets, cursors, block_sums);
    scatter_perm<<<(ECNT + 255) / 256, 256, 0, stream>>>(index, cursors, perm);

    long long gthreads = (long long)NROWS * 64;
    int gblocks = (int)((gthreads + 255) / 256);
    gather_rows<<<gblocks, 256, 0, stream>>>(A, B, perm, offsets, counts, out);
}